// Round 1
// baseline (356.822 us; speedup 1.0000x reference)
//
#include <hip/hip_runtime.h>

// ---- problem constants ----
#define B_   64
#define L_   256
#define E_   1600
#define P_   100
#define KP   4
// output layout (flat float32 concat, reference return order)
#define N0 34
#define N1 33
#define N2 33
#define LOUT0 253
#define LOUT1 250
#define LOUT2 247
#define OFF_PD 0
#define OFF_D0 6400
#define OFF_D1 (OFF_D0 + B_*N0*LOUT0)   // 556928
#define OFF_D2 (OFF_D1 + B_*N1*LOUT1)   // 1084928
#define OFF_CO (OFF_D2 + B_*N2*LOUT2)   // 1606592

// ---- main GEMM tiling ----
#define TM   144          // rows per block (256-112 -> no row masking)
#define TNB  80           // cols per block (20 protos x 4 taps), 400 = 5*80
#define BK   32           // bf16 K-chunk
#define APAD 8
#define ASTR (BK + APAD)  // 40 bf16 elems LDS row stride
#define YSTR 81           // fp32 Y LDS stride (conflict-break)

typedef float f32x4 __attribute__((ext_vector_type(4)));
typedef unsigned short ushort8v __attribute__((ext_vector_type(8)));
typedef __bf16 bf16x8 __attribute__((ext_vector_type(8)));

__device__ __forceinline__ unsigned short bf16rne(float f) {
    unsigned u = __float_as_uint(f);
    u += 0x7FFFu + ((u >> 16) & 1u);
    return (unsigned short)(u >> 16);
}

// ---------------------------------------------------------------------------
// prep: s[b,l] = sum_e emb^2 ; p2[p] = sum proto^2 ; init proto_dist to +INF
// ---------------------------------------------------------------------------
__global__ __launch_bounds__(256) void proto_prep_kernel(
        const float* __restrict__ emb, const float* __restrict__ proto,
        float* __restrict__ ws_s, float* __restrict__ ws_p2,
        float* __restrict__ out) {
    int q = blockIdx.x;
    int wave = threadIdx.x >> 6, lane = threadIdx.x & 63;
    if (q < 4096) {                      // s rows: one wave per (b,l) row
        int row = q * 4 + wave;          // [0,16384)
        const float4* r = (const float4*)(emb + (size_t)row * E_);
        float acc = 0.f;
        #pragma unroll
        for (int it = 0; it < 7; ++it) {
            int e4 = it * 64 + lane;
            if (e4 < 400) {
                float4 v = r[e4];
                acc += v.x*v.x + v.y*v.y + v.z*v.z + v.w*v.w;
            }
        }
        #pragma unroll
        for (int off = 32; off; off >>= 1) acc += __shfl_down(acc, off);
        if (lane == 0) ws_s[row] = acc;
    } else if (q < 4121) {               // p2: one wave per proto
        int p = (q - 4096) * 4 + wave;
        if (p < P_) {
            const float4* r = (const float4*)(proto + (size_t)p * (E_ * KP));
            float acc = 0.f;
            #pragma unroll
            for (int it = 0; it < 25; ++it) {
                float4 v = r[it * 64 + lane];
                acc += v.x*v.x + v.y*v.y + v.z*v.z + v.w*v.w;
            }
            #pragma unroll
            for (int off = 32; off; off >>= 1) acc += __shfl_down(acc, off);
            if (lane == 0) ws_p2[p] = acc;
        }
    } else {                             // init proto_dist to +INF
        for (int i = threadIdx.x; i < B_ * P_; i += 256)
            out[OFF_PD + i] = __uint_as_float(0x7F800000u);
    }
}

// ---------------------------------------------------------------------------
// main: Y = A(bf16) @ W^T(bf16) per (b, half, col-tile) with +16-row halo,
// fused dist epilogue + per-proto block min -> atomicMin into proto_dist
// ---------------------------------------------------------------------------
__global__ __launch_bounds__(192) void proto_main_kernel(
        const float* __restrict__ emb, const float* __restrict__ proto,
        const float* __restrict__ ws_s, const float* __restrict__ ws_p2,
        float* __restrict__ out) {

    __shared__ __align__(16) char smem[47392];
    unsigned short* Ald = (unsigned short*)smem;                 // [144][ASTR]
    unsigned short* Bld = (unsigned short*)(smem + TM*ASTR*2);   // [80][ASTR]

    int bx = blockIdx.x;
    int n_blk = bx % 5;
    int m     = (bx / 5) & 1;
    int b     = bx / 10;
    int r0    = m ? 112 : 0;
    int pbase = n_blk * 20;

    const float* Abase = emb + ((size_t)(b * L_ + r0)) * E_;
    const float* Bbase = proto + (size_t)pbase * (E_ * KP);

    int tid  = threadIdx.x;
    int lane = tid & 63;
    int wave = tid >> 6;
    int mrow = lane & 15;
    int kq   = (lane >> 4) * 8;

    f32x4 acc[3][5] = {};

    for (int c = 0; c < E_ / BK; ++c) {
        int e0 = c * BK;
        // stage A tile 144x32 (fp32 global -> bf16 LDS), coalesced float4
        #pragma unroll
        for (int i = 0; i < 6; ++i) {
            int idx = tid + i * 192;
            int row = idx >> 3;
            int e4  = idx & 7;
            float4 v = *(const float4*)(Abase + (size_t)row * E_ + e0 + e4 * 4);
            ushort4 bv = make_ushort4(bf16rne(v.x), bf16rne(v.y),
                                      bf16rne(v.z), bf16rne(v.w));
            *(ushort4*)&Ald[row * ASTR + e4 * 4] = bv;
        }
        // stage B tile: Bt[n=4p+k][e] from proto[p][e][0..3] float4 reads
        for (int idx = tid; idx < 640; idx += 192) {
            int pl = idx >> 5;
            int el = idx & 31;
            float4 v = *(const float4*)(Bbase + (size_t)pl * (E_ * KP)
                                        + (size_t)(e0 + el) * KP);
            Bld[(4*pl + 0) * ASTR + el] = bf16rne(v.x);
            Bld[(4*pl + 1) * ASTR + el] = bf16rne(v.y);
            Bld[(4*pl + 2) * ASTR + el] = bf16rne(v.z);
            Bld[(4*pl + 3) * ASTR + el] = bf16rne(v.w);
        }
        __syncthreads();

        ushort8v af[3], bfr[5];
        #pragma unroll
        for (int mi = 0; mi < 3; ++mi)
            af[mi] = *(const ushort8v*)&Ald[(wave*48 + mi*16 + mrow) * ASTR + kq];
        #pragma unroll
        for (int ni = 0; ni < 5; ++ni)
            bfr[ni] = *(const ushort8v*)&Bld[(ni*16 + mrow) * ASTR + kq];
        #pragma unroll
        for (int mi = 0; mi < 3; ++mi)
            #pragma unroll
            for (int ni = 0; ni < 5; ++ni)
                acc[mi][ni] = __builtin_amdgcn_mfma_f32_16x16x32_bf16(
                    __builtin_bit_cast(bf16x8, af[mi]),
                    __builtin_bit_cast(bf16x8, bfr[ni]),
                    acc[mi][ni], 0, 0, 0);
        __syncthreads();
    }

    // ---- epilogue: Y -> LDS, form distances ----
    float*    Ylds   = (float*)smem;                    // [144][YSTR]
    float*    slds   = (float*)(smem + TM * YSTR * 4);  // [144]
    float*    p2lds  = slds + TM;                       // [20]
    unsigned* minlds = (unsigned*)(p2lds + 20);         // [20]

    {
        int colq = lane & 15;
        int rowq = (lane >> 4) * 4;
        #pragma unroll
        for (int mi = 0; mi < 3; ++mi) {
            int row = wave * 48 + mi * 16 + rowq;
            #pragma unroll
            for (int ni = 0; ni < 5; ++ni) {
                int col = ni * 16 + colq;
                #pragma unroll
                for (int r = 0; r < 4; ++r)
                    Ylds[(row + r) * YSTR + col] = acc[mi][ni][r];
            }
        }
    }
    if (tid < TM) slds[tid] = ws_s[b * L_ + r0 + tid];
    if (tid < 20) { p2lds[tid] = ws_p2[pbase + tid]; minlds[tid] = 0x7F800000u; }
    __syncthreads();

    int l_lo = m * 128;
    for (int idx = tid; idx < 20 * 128; idx += 192) {
        int pl  = idx >> 7;
        int lof = idx & 127;
        int p = pbase + pl;
        int d, Lout, nseg, pseg; size_t segbase;
        if (p < 34)      { d = 1; Lout = LOUT0; segbase = OFF_D0; pseg = p;      nseg = N0; }
        else if (p < 67) { d = 2; Lout = LOUT1; segbase = OFF_D1; pseg = p - 34; nseg = N1; }
        else             { d = 3; Lout = LOUT2; segbase = OFF_D2; pseg = p - 67; nseg = N2; }
        int l = l_lo + lof;
        if (l < Lout) {
            int rl = l - r0;
            int c0 = pl * 4;
            float xp = Ylds[rl * YSTR + c0]
                     + Ylds[(rl + d) * YSTR + c0 + 1]
                     + Ylds[(rl + 2*d) * YSTR + c0 + 2]
                     + Ylds[(rl + 3*d) * YSTR + c0 + 3];
            float x2 = slds[rl] + slds[rl + d] + slds[rl + 2*d] + slds[rl + 3*d];
            float dist = sqrtf(fabsf(x2 - 2.f * xp + p2lds[pl]));
            out[segbase + ((size_t)b * nseg + pseg) * Lout + l] = dist;
            atomicMin(&minlds[pl], __float_as_uint(dist));
        }
    }
    __syncthreads();
    if (tid < 20)
        atomicMin((unsigned*)out + OFF_PD + b * P_ + pbase + tid, minlds[tid]);
}

// ---------------------------------------------------------------------------
// fc: class_out[b,c] = sum_p proto_dist[b,p] * fc_w[c,p]
// ---------------------------------------------------------------------------
__global__ __launch_bounds__(128) void proto_fc_kernel(
        const float* __restrict__ fc_w, float* __restrict__ out) {
    int t = threadIdx.x;      // 128 = 64 b * 2 c
    int b = t >> 1, c = t & 1;
    const float* pd = out + OFF_PD + b * P_;
    const float* w  = fc_w + c * P_;
    float s = 0.f;
    #pragma unroll 4
    for (int p = 0; p < P_; ++p) s += pd[p] * w[p];
    out[OFF_CO + b * 2 + c] = s;
}

extern "C" void kernel_launch(void* const* d_in, const int* in_sizes, int n_in,
                              void* d_out, int out_size, void* d_ws, size_t ws_size,
                              hipStream_t stream) {
    const float* emb   = (const float*)d_in[0];   // [64,256,1600]
    const float* proto = (const float*)d_in[1];   // [100,1600,4]
    const float* fc_w  = (const float*)d_in[2];   // [2,100]
    float* out  = (float*)d_out;
    float* ws_s  = (float*)d_ws;                  // 16384 floats
    float* ws_p2 = ws_s + B_ * L_;                // 100 floats

    proto_prep_kernel<<<4122, 256, 0, stream>>>(emb, proto, ws_s, ws_p2, out);
    proto_main_kernel<<<640, 192, 0, stream>>>(emb, proto, ws_s, ws_p2, out);
    proto_fc_kernel<<<1, 128, 0, stream>>>(fc_w, out);
}

// Round 2
// 218.763 us; speedup vs baseline: 1.6311x; 1.6311x over previous
//
#include <hip/hip_runtime.h>

// ---- problem constants ----
#define B_   64
#define L_   256
#define E_   1600
#define P_   100
#define KP   4
// output layout (flat float32 concat, reference return order)
#define N0 34
#define N1 33
#define N2 33
#define LOUT0 253
#define LOUT1 250
#define LOUT2 247
#define OFF_PD 0
#define OFF_D0 6400
#define OFF_D1 (OFF_D0 + B_*N0*LOUT0)   // 556928
#define OFF_D2 (OFF_D1 + B_*N1*LOUT1)   // 1084928
#define OFF_CO (OFF_D2 + B_*N2*LOUT2)   // 1606592

// ---- ws layout (fast path, bf16 pre-converted operands) ----
#define WS_ABF  0ull                          // bf16 [16384][1600]
#define WS_BT   52428800ull                   // bf16 [400][1600] (col-major GEMM B^T)
#define WS_S    (WS_BT + 1280000ull)          // f32 [16384]
#define WS_P2   (WS_S + 65536ull)             // f32 [128]
#define WS_NEED (WS_P2 + 512ull)              // ~53.8 MB

// ---- main GEMM tiling (fast path) ----
#define TM   144          // rows per block (256-112 -> no row masking)
#define BKB  128          // K-chunk bytes per row (64 bf16)
// LDS: A [144][128B] @0, B [80][128B] @18432 ; total 28672
#define BOFF 18432

typedef float f32x4 __attribute__((ext_vector_type(4)));
typedef unsigned short ushort8v __attribute__((ext_vector_type(8)));
typedef __bf16 bf16x8 __attribute__((ext_vector_type(8)));
typedef _Float16 f16;

__device__ __forceinline__ unsigned short bf16rne(float f) {
    unsigned u = __float_as_uint(f);
    u += 0x7FFFu + ((u >> 16) & 1u);
    return (unsigned short)(u >> 16);
}

typedef __attribute__((address_space(3))) void lds_void_t;
typedef __attribute__((address_space(1))) void glb_void_t;

__device__ __forceinline__ void gload16(const void* g, void* l) {
    // async global->LDS, 16B/lane; LDS dest = wave-uniform base + lane*16
    __builtin_amdgcn_global_load_lds((const glb_void_t*)g, (lds_void_t*)l, 16, 0, 0);
}

// ===========================================================================
// FAST PATH
// ===========================================================================

// prep: emb fp32 -> bf16 ws (+ s rows); proto fp32 -> B^T bf16 ws (+ p2);
// init proto_dist to +INF
__global__ __launch_bounds__(256) void proto_prep_fast(
        const float* __restrict__ emb, const float* __restrict__ proto,
        char* __restrict__ ws, float* __restrict__ out) {
    int q = blockIdx.x;
    int wave = threadIdx.x >> 6, lane = threadIdx.x & 63;
    if (q < 4096) {                      // emb rows: one wave per (b,l) row
        int row = q * 4 + wave;          // [0,16384)
        const float4* r = (const float4*)(emb + (size_t)row * E_);
        unsigned short* dst = (unsigned short*)(ws + WS_ABF + (size_t)row * (E_*2));
        float acc = 0.f;
        #pragma unroll
        for (int it = 0; it < 6; ++it) {
            int e4 = it * 64 + lane;
            float4 v = r[e4];
            acc += v.x*v.x + v.y*v.y + v.z*v.z + v.w*v.w;
            ushort4 bv = make_ushort4(bf16rne(v.x), bf16rne(v.y),
                                      bf16rne(v.z), bf16rne(v.w));
            *(ushort4*)(dst + e4 * 4) = bv;
        }
        if (lane < 16) {
            int e4 = 384 + lane;
            float4 v = r[e4];
            acc += v.x*v.x + v.y*v.y + v.z*v.z + v.w*v.w;
            ushort4 bv = make_ushort4(bf16rne(v.x), bf16rne(v.y),
                                      bf16rne(v.z), bf16rne(v.w));
            *(ushort4*)(dst + e4 * 4) = bv;
        }
        #pragma unroll
        for (int off = 32; off; off >>= 1) acc += __shfl_down(acc, off);
        if (lane == 0) ((float*)(ws + WS_S))[row] = acc;
    } else if (q < 4121) {               // protos: one wave per proto
        int p = (q - 4096) * 4 + wave;
        if (p < P_) {
            const float4* r = (const float4*)(proto + (size_t)p * (E_ * KP));
            unsigned short* bt = (unsigned short*)(ws + WS_BT);
            float acc = 0.f;
            #pragma unroll
            for (int it = 0; it < 25; ++it) {
                int e = it * 64 + lane;
                float4 v = r[e];
                acc += v.x*v.x + v.y*v.y + v.z*v.z + v.w*v.w;
                bt[(size_t)(4*p + 0) * E_ + e] = bf16rne(v.x);
                bt[(size_t)(4*p + 1) * E_ + e] = bf16rne(v.y);
                bt[(size_t)(4*p + 2) * E_ + e] = bf16rne(v.z);
                bt[(size_t)(4*p + 3) * E_ + e] = bf16rne(v.w);
            }
            #pragma unroll
            for (int off = 32; off; off >>= 1) acc += __shfl_down(acc, off);
            if (lane == 0) ((float*)(ws + WS_P2))[p] = acc;
        }
    } else {                             // init proto_dist to +INF
        for (int i = threadIdx.x; i < B_ * P_; i += 256)
            out[OFF_PD + i] = __uint_as_float(0x7F800000u);
    }
}

// main: 144x80 tile GEMM over K=1600 via global_load_lds staging (bf16),
// XOR-swizzled LDS, fused dist epilogue (fp16 Y round-trip) + proto-min
__global__ __launch_bounds__(192, 4) void proto_main_fast(
        const char* __restrict__ ws, float* __restrict__ out) {

    __shared__ __align__(16) char smem[28672];

    // XCD swizzle: all 10 blocks of one b on the same XCD (bx%8 heuristic)
    int bx0 = blockIdx.x;                   // 0..639
    int lb  = (bx0 & 7) * 80 + (bx0 >> 3);  // bijective remap
    int b     = lb / 10;
    int inner = lb % 10;
    int m     = inner / 5;
    int n_blk = inner % 5;
    int r0    = m ? 112 : 0;
    int pbase = n_blk * 20;

    const char* Ag = ws + WS_ABF + (size_t)(b * L_ + r0) * (E_ * 2);
    const char* Bg = ws + WS_BT  + (size_t)(pbase * 4) * (E_ * 2);

    int tid  = threadIdx.x;
    int lane = tid & 63;
    int wave = tid >> 6;
    int mrow = lane & 15;
    int jq   = lane >> 4;        // 0..3 (16B unit within 64B K-step)
    int lrow8 = lane >> 3;       // 0..7 (row within 8-row wave chunk)
    int jst   = lane & 7;        // stored 16B slot within 128B row

    f32x4 acc[3][5] = {};

    for (int c = 0; c < 25; ++c) {
        int eoff = c * BKB;
        // 28 wave-chunks of 1KB: A chunks 0..17 (144 rows), B chunks 18..27 (80)
        for (int t = wave; t < 28; t += 3) {
            if (t < 18) {
                int rowl = t * 8 + lrow8;
                int j = jst ^ (rowl & 7);
                gload16(Ag + (size_t)rowl * (E_*2) + eoff + j * 16,
                        smem + t * 1024);
            } else {
                int rowl = (t - 18) * 8 + lrow8;
                int j = jst ^ (rowl & 7);
                gload16(Bg + (size_t)rowl * (E_*2) + eoff + j * 16,
                        smem + BOFF + (t - 18) * 1024);
            }
        }
        __syncthreads();

        #pragma unroll
        for (int ks = 0; ks < 2; ++ks) {
            ushort8v af[3], bfv[5];
            #pragma unroll
            for (int mi = 0; mi < 3; ++mi) {
                int rowl = wave * 48 + mi * 16 + mrow;
                af[mi] = *(const ushort8v*)(smem + rowl * 128
                            + (((ks << 2) + jq) ^ (rowl & 7)) * 16);
            }
            #pragma unroll
            for (int ni = 0; ni < 5; ++ni) {
                int rown = ni * 16 + mrow;
                bfv[ni] = *(const ushort8v*)(smem + BOFF + rown * 128
                            + (((ks << 2) + jq) ^ (rown & 7)) * 16);
            }
            #pragma unroll
            for (int mi = 0; mi < 3; ++mi)
                #pragma unroll
                for (int ni = 0; ni < 5; ++ni)
                    acc[mi][ni] = __builtin_amdgcn_mfma_f32_16x16x32_bf16(
                        __builtin_bit_cast(bf16x8, af[mi]),
                        __builtin_bit_cast(bf16x8, bfv[ni]),
                        acc[mi][ni], 0, 0, 0);
        }
        __syncthreads();
    }

    // ---- epilogue: Y (fp16) -> LDS, form distances ----
    f16*      Yh     = (f16*)smem;                    // [144][81]
    float*    slds   = (float*)(smem + 23328);        // [144]
    float*    p2lds  = slds + TM;                     // [20]
    unsigned* minlds = (unsigned*)(p2lds + 20);       // [20]

    {
        int colq = lane & 15;
        int rowq = (lane >> 4) * 4;
        #pragma unroll
        for (int mi = 0; mi < 3; ++mi) {
            int row = wave * 48 + mi * 16 + rowq;
            #pragma unroll
            for (int ni = 0; ni < 5; ++ni) {
                int col = ni * 16 + colq;
                #pragma unroll
                for (int r = 0; r < 4; ++r)
                    Yh[(row + r) * 81 + col] = (f16)acc[mi][ni][r];
            }
        }
    }
    if (tid < TM) slds[tid] = ((const float*)(ws + WS_S))[b * L_ + r0 + tid];
    if (tid < 20) {
        p2lds[tid] = ((const float*)(ws + WS_P2))[pbase + tid];
        minlds[tid] = 0x7F800000u;
    }
    __syncthreads();

    int l_lo = m * 128;
    for (int idx = tid; idx < 20 * 128; idx += 192) {
        int pl  = idx >> 7;
        int lof = idx & 127;
        int p = pbase + pl;
        int d, Lout, nseg, pseg; size_t segbase;
        if (p < 34)      { d = 1; Lout = LOUT0; segbase = OFF_D0; pseg = p;      nseg = N0; }
        else if (p < 67) { d = 2; Lout = LOUT1; segbase = OFF_D1; pseg = p - 34; nseg = N1; }
        else             { d = 3; Lout = LOUT2; segbase = OFF_D2; pseg = p - 67; nseg = N2; }
        int l = l_lo + lof;
        if (l < Lout) {
            int rl = l - r0;
            int c0 = pl * 4;
            float xp = (float)Yh[rl * 81 + c0]
                     + (float)Yh[(rl + d) * 81 + c0 + 1]
                     + (float)Yh[(rl + 2*d) * 81 + c0 + 2]
                     + (float)Yh[(rl + 3*d) * 81 + c0 + 3];
            float x2 = slds[rl] + slds[rl + d] + slds[rl + 2*d] + slds[rl + 3*d];
            float dist = sqrtf(fabsf(x2 - 2.f * xp + p2lds[pl]));
            out[segbase + ((size_t)b * nseg + pseg) * Lout + l] = dist;
            atomicMin(&minlds[pl], __float_as_uint(dist));
        }
    }
    __syncthreads();
    if (tid < 20)
        atomicMin((unsigned*)out + OFF_PD + b * P_ + pbase + tid, minlds[tid]);
}

// ===========================================================================
// FALLBACK PATH (round-1 kernels, used only if ws too small)
// ===========================================================================
#define ASTR 40
#define YSTR 81

__global__ __launch_bounds__(256) void proto_prep_kernel(
        const float* __restrict__ emb, const float* __restrict__ proto,
        float* __restrict__ ws_s, float* __restrict__ ws_p2,
        float* __restrict__ out) {
    int q = blockIdx.x;
    int wave = threadIdx.x >> 6, lane = threadIdx.x & 63;
    if (q < 4096) {
        int row = q * 4 + wave;
        const float4* r = (const float4*)(emb + (size_t)row * E_);
        float acc = 0.f;
        #pragma unroll
        for (int it = 0; it < 7; ++it) {
            int e4 = it * 64 + lane;
            if (e4 < 400) {
                float4 v = r[e4];
                acc += v.x*v.x + v.y*v.y + v.z*v.z + v.w*v.w;
            }
        }
        #pragma unroll
        for (int off = 32; off; off >>= 1) acc += __shfl_down(acc, off);
        if (lane == 0) ws_s[row] = acc;
    } else if (q < 4121) {
        int p = (q - 4096) * 4 + wave;
        if (p < P_) {
            const float4* r = (const float4*)(proto + (size_t)p * (E_ * KP));
            float acc = 0.f;
            #pragma unroll
            for (int it = 0; it < 25; ++it) {
                float4 v = r[it * 64 + lane];
                acc += v.x*v.x + v.y*v.y + v.z*v.z + v.w*v.w;
            }
            #pragma unroll
            for (int off = 32; off; off >>= 1) acc += __shfl_down(acc, off);
            if (lane == 0) ws_p2[p] = acc;
        }
    } else {
        for (int i = threadIdx.x; i < B_ * P_; i += 256)
            out[OFF_PD + i] = __uint_as_float(0x7F800000u);
    }
}

__global__ __launch_bounds__(192) void proto_main_kernel(
        const float* __restrict__ emb, const float* __restrict__ proto,
        const float* __restrict__ ws_s, const float* __restrict__ ws_p2,
        float* __restrict__ out) {

    __shared__ __align__(16) char smem[47392];
    unsigned short* Ald = (unsigned short*)smem;
    unsigned short* Bld = (unsigned short*)(smem + TM*ASTR*2);

    int bx = blockIdx.x;
    int n_blk = bx % 5;
    int m     = (bx / 5) & 1;
    int b     = bx / 10;
    int r0    = m ? 112 : 0;
    int pbase = n_blk * 20;

    const float* Abase = emb + ((size_t)(b * L_ + r0)) * E_;
    const float* Bbase = proto + (size_t)pbase * (E_ * KP);

    int tid  = threadIdx.x;
    int lane = tid & 63;
    int wave = tid >> 6;
    int mrow = lane & 15;
    int kq   = (lane >> 4) * 8;

    f32x4 acc[3][5] = {};

    for (int c = 0; c < E_ / 32; ++c) {
        int e0 = c * 32;
        #pragma unroll
        for (int i = 0; i < 6; ++i) {
            int idx = tid + i * 192;
            int row = idx >> 3;
            int e4  = idx & 7;
            float4 v = *(const float4*)(Abase + (size_t)row * E_ + e0 + e4 * 4);
            ushort4 bv = make_ushort4(bf16rne(v.x), bf16rne(v.y),
                                      bf16rne(v.z), bf16rne(v.w));
            *(ushort4*)&Ald[row * ASTR + e4 * 4] = bv;
        }
        for (int idx = tid; idx < 640; idx += 192) {
            int pl = idx >> 5;
            int el = idx & 31;
            float4 v = *(const float4*)(Bbase + (size_t)pl * (E_ * KP)
                                        + (size_t)(e0 + el) * KP);
            Bld[(4*pl + 0) * ASTR + el] = bf16rne(v.x);
            Bld[(4*pl + 1) * ASTR + el] = bf16rne(v.y);
            Bld[(4*pl + 2) * ASTR + el] = bf16rne(v.z);
            Bld[(4*pl + 3) * ASTR + el] = bf16rne(v.w);
        }
        __syncthreads();

        ushort8v af[3], bfr[5];
        #pragma unroll
        for (int mi = 0; mi < 3; ++mi)
            af[mi] = *(const ushort8v*)&Ald[(wave*48 + mi*16 + mrow) * ASTR + kq];
        #pragma unroll
        for (int ni = 0; ni < 5; ++ni)
            bfr[ni] = *(const ushort8v*)&Bld[(ni*16 + mrow) * ASTR + kq];
        #pragma unroll
        for (int mi = 0; mi < 3; ++mi)
            #pragma unroll
            for (int ni = 0; ni < 5; ++ni)
                acc[mi][ni] = __builtin_amdgcn_mfma_f32_16x16x32_bf16(
                    __builtin_bit_cast(bf16x8, af[mi]),
                    __builtin_bit_cast(bf16x8, bfr[ni]),
                    acc[mi][ni], 0, 0, 0);
        __syncthreads();
    }

    float*    Ylds   = (float*)smem;
    float*    slds   = (float*)(smem + TM * YSTR * 4);
    float*    p2lds  = slds + TM;
    unsigned* minlds = (unsigned*)(p2lds + 20);

    {
        int colq = lane & 15;
        int rowq = (lane >> 4) * 4;
        #pragma unroll
        for (int mi = 0; mi < 3; ++mi) {
            int row = wave * 48 + mi * 16 + rowq;
            #pragma unroll
            for (int ni = 0; ni < 5; ++ni) {
                int col = ni * 16 + colq;
                #pragma unroll
                for (int r = 0; r < 4; ++r)
                    Ylds[(row + r) * YSTR + col] = acc[mi][ni][r];
            }
        }
    }
    if (tid < TM) slds[tid] = ws_s[b * L_ + r0 + tid];
    if (tid < 20) { p2lds[tid] = ws_p2[pbase + tid]; minlds[tid] = 0x7F800000u; }
    __syncthreads();

    int l_lo = m * 128;
    for (int idx = tid; idx < 20 * 128; idx += 192) {
        int pl  = idx >> 7;
        int lof = idx & 127;
        int p = pbase + pl;
        int d, Lout, nseg, pseg; size_t segbase;
        if (p < 34)      { d = 1; Lout = LOUT0; segbase = OFF_D0; pseg = p;      nseg = N0; }
        else if (p < 67) { d = 2; Lout = LOUT1; segbase = OFF_D1; pseg = p - 34; nseg = N1; }
        else             { d = 3; Lout = LOUT2; segbase = OFF_D2; pseg = p - 67; nseg = N2; }
        int l = l_lo + lof;
        if (l < Lout) {
            int rl = l - r0;
            int c0 = pl * 4;
            float xp = Ylds[rl * YSTR + c0]
                     + Ylds[(rl + d) * YSTR + c0 + 1]
                     + Ylds[(rl + 2*d) * YSTR + c0 + 2]
                     + Ylds[(rl + 3*d) * YSTR + c0 + 3];
            float x2 = slds[rl] + slds[rl + d] + slds[rl + 2*d] + slds[rl + 3*d];
            float dist = sqrtf(fabsf(x2 - 2.f * xp + p2lds[pl]));
            out[segbase + ((size_t)b * nseg + pseg) * Lout + l] = dist;
            atomicMin(&minlds[pl], __float_as_uint(dist));
        }
    }
    __syncthreads();
    if (tid < 20)
        atomicMin((unsigned*)out + OFF_PD + b * P_ + pbase + tid, minlds[tid]);
}

// ---------------------------------------------------------------------------
// fc: class_out[b,c] = sum_p proto_dist[b,p] * fc_w[c,p]
// ---------------------------------------------------------------------------
__global__ __launch_bounds__(128) void proto_fc_kernel(
        const float* __restrict__ fc_w, float* __restrict__ out) {
    int t = threadIdx.x;      // 128 = 64 b * 2 c
    int b = t >> 1, c = t & 1;
    const float* pd = out + OFF_PD + b * P_;
    const float* w  = fc_w + c * P_;
    float s = 0.f;
    #pragma unroll 4
    for (int p = 0; p < P_; ++p) s += pd[p] * w[p];
    out[OFF_CO + b * 2 + c] = s;
}

extern "C" void kernel_launch(void* const* d_in, const int* in_sizes, int n_in,
                              void* d_out, int out_size, void* d_ws, size_t ws_size,
                              hipStream_t stream) {
    const float* emb   = (const float*)d_in[0];   // [64,256,1600]
    const float* proto = (const float*)d_in[1];   // [100,1600,4]
    const float* fc_w  = (const float*)d_in[2];   // [2,100]
    float* out  = (float*)d_out;

    if (ws_size >= WS_NEED) {
        char* ws = (char*)d_ws;
        proto_prep_fast<<<4122, 256, 0, stream>>>(emb, proto, ws, out);
        proto_main_fast<<<640, 192, 0, stream>>>(ws, out);
    } else {
        float* ws_s  = (float*)d_ws;              // 16384 floats
        float* ws_p2 = ws_s + B_ * L_;            // 100 floats
        proto_prep_kernel<<<4122, 256, 0, stream>>>(emb, proto, ws_s, ws_p2, out);
        proto_main_kernel<<<640, 192, 0, stream>>>(emb, proto, ws_s, ws_p2, out);
    }
    proto_fc_kernel<<<1, 128, 0, stream>>>(fc_w, out);
}

// Round 3
// 212.322 us; speedup vs baseline: 1.6806x; 1.0303x over previous
//
#include <hip/hip_runtime.h>

// ---- problem constants ----
#define B_   64
#define L_   256
#define E_   1600
#define P_   100
#define KP   4
// output layout (flat float32 concat, reference return order)
#define N0 34
#define N1 33
#define N2 33
#define LOUT0 253
#define LOUT1 250
#define LOUT2 247
#define OFF_PD 0
#define OFF_D0 6400
#define OFF_D1 (OFF_D0 + B_*N0*LOUT0)   // 556928
#define OFF_D2 (OFF_D1 + B_*N1*LOUT1)   // 1084928
#define OFF_CO (OFF_D2 + B_*N2*LOUT2)   // 1606592

// ---- ws layout (fast path, bf16 pre-converted operands) ----
#define WS_ABF  0ull                          // bf16 [16384][1600]
#define WS_BT   52428800ull                   // bf16 [400][1600] (GEMM B^T)
#define WS_S    (WS_BT + 1280000ull)          // f32 [16384]
#define WS_P2   (WS_S + 65536ull)             // f32 [128]
#define WS_NEED (WS_P2 + 512ull)              // ~53.8 MB

// ---- main GEMM tiling (fast path): 96 rows x 80 cols, 6 waves ----
// 3 M-tiles/b (halo 12.5%) x 5 col-groups x 64 b = 960 blocks, all co-resident
#define TMF  96
#define BKB  128          // K-chunk bytes per row (64 bf16)
#define BOFF2 12288       // B tile LDS offset (A = 96*128)

typedef float f32x4 __attribute__((ext_vector_type(4)));
typedef unsigned short ushort8v __attribute__((ext_vector_type(8)));
typedef __bf16 bf16x8 __attribute__((ext_vector_type(8)));
typedef _Float16 f16;

__device__ __forceinline__ unsigned short bf16rne(float f) {
    unsigned u = __float_as_uint(f);
    u += 0x7FFFu + ((u >> 16) & 1u);
    return (unsigned short)(u >> 16);
}

typedef __attribute__((address_space(3))) void lds_void_t;
typedef __attribute__((address_space(1))) void glb_void_t;

__device__ __forceinline__ void gload16(const void* g, void* l) {
    // async global->LDS, 16B/lane; LDS dest = wave-uniform base + lane*16
    __builtin_amdgcn_global_load_lds((const glb_void_t*)g, (lds_void_t*)l, 16, 0, 0);
}

// ===========================================================================
// FAST PATH
// ===========================================================================

// prep: emb fp32 -> bf16 ws (+ s rows); proto fp32 -> B^T bf16 ws (+ p2);
// init proto_dist to +INF
__global__ __launch_bounds__(256) void proto_prep_fast(
        const float* __restrict__ emb, const float* __restrict__ proto,
        char* __restrict__ ws, float* __restrict__ out) {
    int q = blockIdx.x;
    int wave = threadIdx.x >> 6, lane = threadIdx.x & 63;
    if (q < 4096) {                      // emb rows: one wave per (b,l) row
        int row = q * 4 + wave;          // [0,16384)
        const float4* r = (const float4*)(emb + (size_t)row * E_);
        unsigned short* dst = (unsigned short*)(ws + WS_ABF + (size_t)row * (E_*2));
        float acc = 0.f;
        #pragma unroll
        for (int it = 0; it < 6; ++it) {
            int e4 = it * 64 + lane;
            float4 v = r[e4];
            acc += v.x*v.x + v.y*v.y + v.z*v.z + v.w*v.w;
            ushort4 bv = make_ushort4(bf16rne(v.x), bf16rne(v.y),
                                      bf16rne(v.z), bf16rne(v.w));
            *(ushort4*)(dst + e4 * 4) = bv;
        }
        if (lane < 16) {
            int e4 = 384 + lane;
            float4 v = r[e4];
            acc += v.x*v.x + v.y*v.y + v.z*v.z + v.w*v.w;
            ushort4 bv = make_ushort4(bf16rne(v.x), bf16rne(v.y),
                                      bf16rne(v.z), bf16rne(v.w));
            *(ushort4*)(dst + e4 * 4) = bv;
        }
        #pragma unroll
        for (int off = 32; off; off >>= 1) acc += __shfl_down(acc, off);
        if (lane == 0) ((float*)(ws + WS_S))[row] = acc;
    } else if (q < 4121) {               // protos: one wave per proto
        int p = (q - 4096) * 4 + wave;
        if (p < P_) {
            const float4* r = (const float4*)(proto + (size_t)p * (E_ * KP));
            unsigned short* bt = (unsigned short*)(ws + WS_BT);
            float acc = 0.f;
            #pragma unroll
            for (int it = 0; it < 25; ++it) {
                int e = it * 64 + lane;
                float4 v = r[e];
                acc += v.x*v.x + v.y*v.y + v.z*v.z + v.w*v.w;
                bt[(size_t)(4*p + 0) * E_ + e] = bf16rne(v.x);
                bt[(size_t)(4*p + 1) * E_ + e] = bf16rne(v.y);
                bt[(size_t)(4*p + 2) * E_ + e] = bf16rne(v.z);
                bt[(size_t)(4*p + 3) * E_ + e] = bf16rne(v.w);
            }
            #pragma unroll
            for (int off = 32; off; off >>= 1) acc += __shfl_down(acc, off);
            if (lane == 0) ((float*)(ws + WS_P2))[p] = acc;
        }
    } else {                             // init proto_dist to +INF
        for (int i = threadIdx.x; i < B_ * P_; i += 256)
            out[OFF_PD + i] = __uint_as_float(0x7F800000u);
    }
}

// main: 96x80 tile GEMM over K=1600 via global_load_lds (bf16, XOR-swizzled),
// 6 waves/block, grid 960 fully co-resident; fused dist epilogue + proto-min
__global__ __launch_bounds__(384, 6) void proto_main_fast(
        const char* __restrict__ ws, float* __restrict__ out) {

    __shared__ __align__(16) char smem[22528];

    // XCD grouping: xcd = bx&7 (heuristic); 8 consecutive b per XCD,
    // all 15 blocks of one b on the same XCD for A/B L2 reuse
    int bx   = blockIdx.x;               // 0..959
    int lb   = (bx & 7) * 120 + (bx >> 3);
    int b     = lb / 15;
    int inner = lb % 15;
    int m     = inner / 5;
    int n_blk = inner % 5;
    int r0    = (m == 0) ? 0 : (m == 1 ? 87 : 160);
    int l_lo  = m * 87;
    int pbase = n_blk * 20;

    const char* Ag = ws + WS_ABF + (size_t)(b * L_ + r0) * (E_ * 2);
    const char* Bg = ws + WS_BT  + (size_t)(pbase * 4) * (E_ * 2);

    int tid   = threadIdx.x;
    int lane  = tid & 63;
    int wave  = tid >> 6;        // 0..5, one 16-row M-frag per wave
    int mrow  = lane & 15;
    int jq    = lane >> 4;       // 0..3 (16B unit within 64B K-step)
    int lrow8 = lane >> 3;       // 0..7 (row within 8-row staging chunk)
    int jst   = lane & 7;        // stored 16B slot within 128B row

    f32x4 acc[5] = {};

    for (int c = 0; c < 25; ++c) {
        int eoff = c * BKB;
        // 22 wave-chunks of 1KB: A chunks 0..11 (96 rows), B 12..21 (80 rows)
        for (int t = wave; t < 22; t += 6) {
            if (t < 12) {
                int rowl = t * 8 + lrow8;
                int j = jst ^ (rowl & 7);
                gload16(Ag + (size_t)rowl * (E_*2) + eoff + j * 16,
                        smem + t * 1024);
            } else {
                int rowl = (t - 12) * 8 + lrow8;
                int j = jst ^ (rowl & 7);
                gload16(Bg + (size_t)rowl * (E_*2) + eoff + j * 16,
                        smem + BOFF2 + (t - 12) * 1024);
            }
        }
        __syncthreads();

        #pragma unroll
        for (int ks = 0; ks < 2; ++ks) {
            int rowA = wave * 16 + mrow;
            ushort8v af = *(const ushort8v*)(smem + rowA * 128
                            + (((ks << 2) + jq) ^ (rowA & 7)) * 16);
            ushort8v bfv[5];
            #pragma unroll
            for (int ni = 0; ni < 5; ++ni) {
                int rowB = ni * 16 + mrow;
                bfv[ni] = *(const ushort8v*)(smem + BOFF2 + rowB * 128
                            + (((ks << 2) + jq) ^ (rowB & 7)) * 16);
            }
            #pragma unroll
            for (int ni = 0; ni < 5; ++ni)
                acc[ni] = __builtin_amdgcn_mfma_f32_16x16x32_bf16(
                    __builtin_bit_cast(bf16x8, af),
                    __builtin_bit_cast(bf16x8, bfv[ni]),
                    acc[ni], 0, 0, 0);
        }
        __syncthreads();
    }

    // ---- epilogue: Y (fp16) -> LDS, form distances ----
    f16*      Yh     = (f16*)smem;                    // [96][81]
    float*    slds   = (float*)(smem + 15552);        // [96]
    float*    p2lds  = slds + TMF;                    // [20]
    unsigned* minlds = (unsigned*)(p2lds + 20);       // [20]

    {
        int colq = lane & 15;
        int rowq = (lane >> 4) * 4;
        int row = wave * 16 + rowq;
        #pragma unroll
        for (int ni = 0; ni < 5; ++ni) {
            int col = ni * 16 + colq;
            #pragma unroll
            for (int r = 0; r < 4; ++r)
                Yh[(row + r) * 81 + col] = (f16)acc[ni][r];
        }
    }
    if (tid < TMF) slds[tid] = ((const float*)(ws + WS_S))[b * L_ + r0 + tid];
    if (tid < 20) {
        p2lds[tid] = ((const float*)(ws + WS_P2))[pbase + tid];
        minlds[tid] = 0x7F800000u;
    }
    __syncthreads();

    // l-range for this m-tile: [l_lo, l_lo+87) ∩ [0, Lout)
    for (int idx = tid; idx < 20 * 87; idx += 384) {
        int pl  = idx / 87;
        int lof = idx % 87;
        int p = pbase + pl;
        int d, Lout, nseg, pseg; size_t segbase;
        if (p < 34)      { d = 1; Lout = LOUT0; segbase = OFF_D0; pseg = p;      nseg = N0; }
        else if (p < 67) { d = 2; Lout = LOUT1; segbase = OFF_D1; pseg = p - 34; nseg = N1; }
        else             { d = 3; Lout = LOUT2; segbase = OFF_D2; pseg = p - 67; nseg = N2; }
        int l = l_lo + lof;
        if (l < Lout) {
            int rl = l - r0;
            int c0 = pl * 4;
            float xp = (float)Yh[rl * 81 + c0]
                     + (float)Yh[(rl + d) * 81 + c0 + 1]
                     + (float)Yh[(rl + 2*d) * 81 + c0 + 2]
                     + (float)Yh[(rl + 3*d) * 81 + c0 + 3];
            float x2 = slds[rl] + slds[rl + d] + slds[rl + 2*d] + slds[rl + 3*d];
            float dist = sqrtf(fabsf(x2 - 2.f * xp + p2lds[pl]));
            out[segbase + ((size_t)b * nseg + pseg) * Lout + l] = dist;
            atomicMin(&minlds[pl], __float_as_uint(dist));
        }
    }
    __syncthreads();
    if (tid < 20)
        atomicMin((unsigned*)out + OFF_PD + b * P_ + pbase + tid, minlds[tid]);
}

// ===========================================================================
// FALLBACK PATH (round-1 kernels, used only if ws too small)
// ===========================================================================
#define TM   144
#define ASTR 40
#define YSTR 81

__global__ __launch_bounds__(256) void proto_prep_kernel(
        const float* __restrict__ emb, const float* __restrict__ proto,
        float* __restrict__ ws_s, float* __restrict__ ws_p2,
        float* __restrict__ out) {
    int q = blockIdx.x;
    int wave = threadIdx.x >> 6, lane = threadIdx.x & 63;
    if (q < 4096) {
        int row = q * 4 + wave;
        const float4* r = (const float4*)(emb + (size_t)row * E_);
        float acc = 0.f;
        #pragma unroll
        for (int it = 0; it < 7; ++it) {
            int e4 = it * 64 + lane;
            if (e4 < 400) {
                float4 v = r[e4];
                acc += v.x*v.x + v.y*v.y + v.z*v.z + v.w*v.w;
            }
        }
        #pragma unroll
        for (int off = 32; off; off >>= 1) acc += __shfl_down(acc, off);
        if (lane == 0) ws_s[row] = acc;
    } else if (q < 4121) {
        int p = (q - 4096) * 4 + wave;
        if (p < P_) {
            const float4* r = (const float4*)(proto + (size_t)p * (E_ * KP));
            float acc = 0.f;
            #pragma unroll
            for (int it = 0; it < 25; ++it) {
                float4 v = r[it * 64 + lane];
                acc += v.x*v.x + v.y*v.y + v.z*v.z + v.w*v.w;
            }
            #pragma unroll
            for (int off = 32; off; off >>= 1) acc += __shfl_down(acc, off);
            if (lane == 0) ws_p2[p] = acc;
        }
    } else {
        for (int i = threadIdx.x; i < B_ * P_; i += 256)
            out[OFF_PD + i] = __uint_as_float(0x7F800000u);
    }
}

__global__ __launch_bounds__(192) void proto_main_kernel(
        const float* __restrict__ emb, const float* __restrict__ proto,
        const float* __restrict__ ws_s, const float* __restrict__ ws_p2,
        float* __restrict__ out) {

    __shared__ __align__(16) char smem[47392];
    unsigned short* Ald = (unsigned short*)smem;
    unsigned short* Bld = (unsigned short*)(smem + TM*ASTR*2);

    int bx = blockIdx.x;
    int n_blk = bx % 5;
    int m     = (bx / 5) & 1;
    int b     = bx / 10;
    int r0    = m ? 112 : 0;
    int pbase = n_blk * 20;

    const float* Abase = emb + ((size_t)(b * L_ + r0)) * E_;
    const float* Bbase = proto + (size_t)pbase * (E_ * KP);

    int tid  = threadIdx.x;
    int lane = tid & 63;
    int wave = tid >> 6;
    int mrow = lane & 15;
    int kq   = (lane >> 4) * 8;

    f32x4 acc[3][5] = {};

    for (int c = 0; c < E_ / 32; ++c) {
        int e0 = c * 32;
        #pragma unroll
        for (int i = 0; i < 6; ++i) {
            int idx = tid + i * 192;
            int row = idx >> 3;
            int e4  = idx & 7;
            float4 v = *(const float4*)(Abase + (size_t)row * E_ + e0 + e4 * 4);
            ushort4 bv = make_ushort4(bf16rne(v.x), bf16rne(v.y),
                                      bf16rne(v.z), bf16rne(v.w));
            *(ushort4*)&Ald[row * ASTR + e4 * 4] = bv;
        }
        for (int idx = tid; idx < 640; idx += 192) {
            int pl = idx >> 5;
            int el = idx & 31;
            float4 v = *(const float4*)(Bbase + (size_t)pl * (E_ * KP)
                                        + (size_t)(e0 + el) * KP);
            Bld[(4*pl + 0) * ASTR + el] = bf16rne(v.x);
            Bld[(4*pl + 1) * ASTR + el] = bf16rne(v.y);
            Bld[(4*pl + 2) * ASTR + el] = bf16rne(v.z);
            Bld[(4*pl + 3) * ASTR + el] = bf16rne(v.w);
        }
        __syncthreads();

        ushort8v af[3], bfr[5];
        #pragma unroll
        for (int mi = 0; mi < 3; ++mi)
            af[mi] = *(const ushort8v*)&Ald[(wave*48 + mi*16 + mrow) * ASTR + kq];
        #pragma unroll
        for (int ni = 0; ni < 5; ++ni)
            bfr[ni] = *(const ushort8v*)&Bld[(ni*16 + mrow) * ASTR + kq];
        #pragma unroll
        for (int mi = 0; mi < 3; ++mi)
            #pragma unroll
            for (int ni = 0; ni < 5; ++ni)
                acc[mi][ni] = __builtin_amdgcn_mfma_f32_16x16x32_bf16(
                    __builtin_bit_cast(bf16x8, af[mi]),
                    __builtin_bit_cast(bf16x8, bfr[ni]),
                    acc[mi][ni], 0, 0, 0);
        __syncthreads();
    }

    float*    Ylds   = (float*)smem;
    float*    slds   = (float*)(smem + TM * YSTR * 4);
    float*    p2lds  = slds + TM;
    unsigned* minlds = (unsigned*)(p2lds + 20);

    {
        int colq = lane & 15;
        int rowq = (lane >> 4) * 4;
        #pragma unroll
        for (int mi = 0; mi < 3; ++mi) {
            int row = wave * 48 + mi * 16 + rowq;
            #pragma unroll
            for (int ni = 0; ni < 5; ++ni) {
                int col = ni * 16 + colq;
                #pragma unroll
                for (int r = 0; r < 4; ++r)
                    Ylds[(row + r) * YSTR + col] = acc[mi][ni][r];
            }
        }
    }
    if (tid < TM) slds[tid] = ws_s[b * L_ + r0 + tid];
    if (tid < 20) { p2lds[tid] = ws_p2[pbase + tid]; minlds[tid] = 0x7F800000u; }
    __syncthreads();

    int l_lo = m * 128;
    for (int idx = tid; idx < 20 * 128; idx += 192) {
        int pl  = idx >> 7;
        int lof = idx & 127;
        int p = pbase + pl;
        int d, Lout, nseg, pseg; size_t segbase;
        if (p < 34)      { d = 1; Lout = LOUT0; segbase = OFF_D0; pseg = p;      nseg = N0; }
        else if (p < 67) { d = 2; Lout = LOUT1; segbase = OFF_D1; pseg = p - 34; nseg = N1; }
        else             { d = 3; Lout = LOUT2; segbase = OFF_D2; pseg = p - 67; nseg = N2; }
        int l = l_lo + lof;
        if (l < Lout) {
            int rl = l - r0;
            int c0 = pl * 4;
            float xp = Ylds[rl * YSTR + c0]
                     + Ylds[(rl + d) * YSTR + c0 + 1]
                     + Ylds[(rl + 2*d) * YSTR + c0 + 2]
                     + Ylds[(rl + 3*d) * YSTR + c0 + 3];
            float x2 = slds[rl] + slds[rl + d] + slds[rl + 2*d] + slds[rl + 3*d];
            float dist = sqrtf(fabsf(x2 - 2.f * xp + p2lds[pl]));
            out[segbase + ((size_t)b * nseg + pseg) * Lout + l] = dist;
            atomicMin(&minlds[pl], __float_as_uint(dist));
        }
    }
    __syncthreads();
    if (tid < 20)
        atomicMin((unsigned*)out + OFF_PD + b * P_ + pbase + tid, minlds[tid]);
}

// ---------------------------------------------------------------------------
// fc: class_out[b,c] = sum_p proto_dist[b,p] * fc_w[c,p]
// ---------------------------------------------------------------------------
__global__ __launch_bounds__(128) void proto_fc_kernel(
        const float* __restrict__ fc_w, float* __restrict__ out) {
    int t = threadIdx.x;      // 128 = 64 b * 2 c
    int b = t >> 1, c = t & 1;
    const float* pd = out + OFF_PD + b * P_;
    const float* w  = fc_w + c * P_;
    float s = 0.f;
    #pragma unroll 4
    for (int p = 0; p < P_; ++p) s += pd[p] * w[p];
    out[OFF_CO + b * 2 + c] = s;
}

extern "C" void kernel_launch(void* const* d_in, const int* in_sizes, int n_in,
                              void* d_out, int out_size, void* d_ws, size_t ws_size,
                              hipStream_t stream) {
    const float* emb   = (const float*)d_in[0];   // [64,256,1600]
    const float* proto = (const float*)d_in[1];   // [100,1600,4]
    const float* fc_w  = (const float*)d_in[2];   // [2,100]
    float* out  = (float*)d_out;

    if (ws_size >= WS_NEED) {
        char* ws = (char*)d_ws;
        proto_prep_fast<<<4122, 256, 0, stream>>>(emb, proto, ws, out);
        proto_main_fast<<<960, 384, 0, stream>>>(ws, out);
    } else {
        float* ws_s  = (float*)d_ws;              // 16384 floats
        float* ws_p2 = ws_s + B_ * L_;            // 100 floats
        proto_prep_kernel<<<4122, 256, 0, stream>>>(emb, proto, ws_s, ws_p2, out);
        proto_main_kernel<<<640, 192, 0, stream>>>(emb, proto, ws_s, ws_p2, out);
    }
    proto_fc_kernel<<<1, 128, 0, stream>>>(fc_w, out);
}